// Round 11
// baseline (195.143 us; speedup 1.0000x reference)
//
#include <hip/hip_runtime.h>

// Problem constants (from reference)
#define NC   32      // feature channels
#define ND1  1024    // line resolution
#define ND2  256     // plane resolution
#define NM   64      // hidden width
#define NPIX (1024 * 1024)
#define NBUCK 256    // 16x16 coarse buckets, each 64x64 coordinate units
#define CAP  4608    // slots per bucket (mean 4096 + 8 sigma)
#define NSLOT (NBUCK * CAP)
#define PW   18      // plane window: 18x18 texels covers any bucket's taps
#define PPADF 36     // floats per texel in LDS (32 + pad, float4-aligned)
#define FBLK 3       // fused blocks per bucket
#define FTH  512     // fused block size
#define PART_SLOTS (CAP / FBLK)     // 1536
#define PART_CHUNKS (PART_SLOTS/16) // 96 chunks of 16 pixels

typedef __attribute__((ext_vector_type(8))) short bf16x8;  // 8 bf16 (4 VGPRs)
typedef __attribute__((ext_vector_type(4))) float f32x4;

__device__ __forceinline__ int clampi(int v, int lo, int hi) {
    return min(max(v, lo), hi);
}

// Split 8 f32 into bf16 hi (truncate) + bf16 lo (exact residual, truncated).
// hi + lo = f with |err| <= 2^-16 |f| per element.
__device__ __forceinline__ void pack_hilo(const float* f, bf16x8& hi, bf16x8& lo) {
    union { unsigned int u[4]; bf16x8 v; } H, L;
#pragma unroll
    for (int j = 0; j < 4; ++j) {
        unsigned int b0 = __float_as_uint(f[2 * j]);
        unsigned int b1 = __float_as_uint(f[2 * j + 1]);
        unsigned int h0 = b0 & 0xFFFF0000u, h1 = b1 & 0xFFFF0000u;
        H.u[j] = (h0 >> 16) | h1;
        float l0 = f[2 * j]     - __uint_as_float(h0);   // exact
        float l1 = f[2 * j + 1] - __uint_as_float(h1);   // exact
        L.u[j] = (__float_as_uint(l0) >> 16) | (__float_as_uint(l1) & 0xFFFF0000u);
    }
    hi = H.v; lo = L.v;
}

// ---------------------------------------------------------------------------
// Pass 1: line transposes (blocks 0..31), cursor init (32), and — only when
// the fallback path needs it — plane transpose (blocks 33..1056).
// ---------------------------------------------------------------------------
__global__ __launch_bounds__(256) void pass1_prepare(
    const float* __restrict__ plane, const float* __restrict__ lfx,
    const float* __restrict__ lfy, float* __restrict__ pl_t,
    float* __restrict__ lx_t, float* __restrict__ ly_t, int* __restrict__ cursor)
{
    __shared__ float tile[32][65];
    const int blk = blockIdx.x, tid = threadIdx.x;
    const float* in; float* out; int N, pos0;
    if (blk < 16)       { in = lfx;   out = lx_t; N = 1024;  pos0 = blk * 64; }
    else if (blk < 32)  { in = lfy;   out = ly_t; N = 1024;  pos0 = (blk - 16) * 64; }
    else if (blk == 32) { if (cursor && tid < NBUCK) cursor[tid] = tid * CAP; return; }
    else                { in = plane; out = pl_t; N = 65536; pos0 = (blk - 33) * 64; }
#pragma unroll
    for (int r = 0; r < 8; ++r) {
        int c = r * 4 + (tid >> 6), p = tid & 63;
        tile[c][p] = in[c * N + pos0 + p];
    }
    __syncthreads();
#pragma unroll
    for (int r = 0; r < 8; ++r) {
        int p = r * 8 + (tid >> 5), c = tid & 31;
        out[(pos0 + p) * 32 + c] = tile[c][p];
    }
}

// ---------------------------------------------------------------------------
// Pass 2: slack-bucket scatter (unchanged from round 9 — measured good).
// ---------------------------------------------------------------------------
__global__ __launch_bounds__(1024) void scatter_slack(
    const float2* __restrict__ coords, int* __restrict__ cursor,
    float4* __restrict__ slots)
{
    __shared__ int h[NBUCK];
    __shared__ int basew[NBUCK];
    const int t = threadIdx.x;
    if (t < NBUCK) h[t] = 0;
    __syncthreads();
    const int base_i = blockIdx.x * 4096;
    float2 xy[4]; int cell[4];
#pragma unroll
    for (int r = 0; r < 4; ++r) {
        xy[r] = coords[base_i + r * 1024 + t];
        const int xi = clampi((int)xy[r].x, 0, 1023);
        const int yi = clampi((int)xy[r].y, 0, 1023);
        cell[r] = ((yi >> 6) << 4) | (xi >> 6);
        atomicAdd(&h[cell[r]], 1);
    }
    __syncthreads();
    if (t < NBUCK) {
        const int n = h[t];
        basew[t] = n ? atomicAdd(&cursor[t], n) : 0;
    }
    __syncthreads();
    if (t < NBUCK) h[t] = 0;
    __syncthreads();
#pragma unroll
    for (int r = 0; r < 4; ++r) {
        const int c   = cell[r];
        const int off = atomicAdd(&h[c], 1);            // LDS atomic
        const int dst = min(basew[c] + off, NSLOT - 1); // defensive clamp
        slots[dst] = make_float4(xy[r].x, xy[r].y,
                                 __int_as_float(base_i + r * 1024 + t), 0.0f);
    }
}

// ---------------------------------------------------------------------------
// Pass 3: MFMA fused kernel. Wave processes 16 pixels/iter: lane l
// interpolates pixel (l&15), channels (l>>4)*8..+8  == A-fragment layout of
// mfma_f32_16x16x32_bf16. W1 as hi/lo bf16 B-fragments preloaded in regs.
// C/D: col=lane&15 (hidden n), row=(lane>>4)*4+r (pixel). Layer 2 via
// 16-lane shfl_xor butterfly.
// ---------------------------------------------------------------------------
__global__ __launch_bounds__(FTH, 4) void fused_mfma(
    const float4* __restrict__ slots, const int* __restrict__ cursor,
    const float* __restrict__ lx,    // [1024][32] transposed
    const float* __restrict__ ly,
    const float* __restrict__ plane, // ORIGINAL [32][256][256]
    const float* __restrict__ W1, const float* __restrict__ b1,
    const float* __restrict__ W2, const float* __restrict__ b2,
    float* __restrict__ out)
{
    const int b    = blockIdx.x / FBLK;
    const int part = blockIdx.x - b * FBLK;
    const int t    = threadIdx.x;
    const int wid  = t >> 6;
    const int lane = t & 63;
    const int lcol = lane & 15;   // A-row (pixel) / B,C-col (hidden)
    const int lq   = lane >> 4;   // k-slice / C row group
    const int bx = b & 15, by = b >> 4;
    const int px0 = (int)(bx * 15.9375f);
    const int py0 = (int)(by * 15.9375f);

    // ---- stage plane window from original layout: pls[tex][c], stride 36 ----
    __shared__ float pls[PW * PW * PPADF];   // 45.6 KB
    for (int i = t; i < PW * PW * 32; i += FTH) {
        const int c = i / (PW * PW), tex = i - c * (PW * PW);
        const int ty = tex / PW, tx = tex - ty * PW;
        const int gy = min(py0 + ty, ND2 - 1), gx = min(px0 + tx, ND2 - 1);
        pls[tex * PPADF + c] = plane[c * 65536 + (gy << 8) + gx];
    }

    // ---- preload B fragments (W1 hi/lo), b1, W2 scalars ----
    bf16x8 bhi[4], blo[4];
    float b1v[4], w2v[4];
#pragma unroll
    for (int nt = 0; nt < 4; ++nt) {
        const int row = nt * 16 + lcol;
        const float4* wr = (const float4*)(W1 + row * NC + lq * 8);
        const float4 wa = wr[0], wb = wr[1];
        float wf[8] = {wa.x, wa.y, wa.z, wa.w, wb.x, wb.y, wb.z, wb.w};
        pack_hilo(wf, bhi[nt], blo[nt]);
        b1v[nt] = b1[row];
        w2v[nt] = W2[row];
    }
    const float b2s = b2[0];
    __syncthreads();

    const int base  = b * CAP;
    const int count = min(cursor[b] - base, CAP);

    for (int ci = wid; ci < PART_CHUNKS; ci += FTH / 64) {
        const int chunk = part * PART_SLOTS + ci * 16;
        if (chunk >= count) break;                   // wave-uniform
        const int s = chunk + lcol;
        const float4 rec = slots[base + min(s, count - 1)];
        const float x = rec.x, y = rec.y;

        const float xn = x * (2.0f / 1024.0f) - 1.0f;
        const float yn = y * (2.0f / 1024.0f) - 1.0f;

        // ---- 1D line interp (border clamp, align_corners) ----
        float posx = fminf(fmaxf((xn + 1.0f) * 0.5f * 1023.0f, 0.0f), 1023.0f);
        int   ix   = min((int)posx, 1022);
        float wx   = posx - (float)ix, omwx = 1.0f - wx;
        float posy = fminf(fmaxf((yn + 1.0f) * 0.5f * 1023.0f, 0.0f), 1023.0f);
        int   iy   = min((int)posy, 1022);
        float wy   = posy - (float)iy, omwy = 1.0f - wy;

        // ---- plane bilinear (zeros padding, align_corners) ----
        float px  = (xn + 1.0f) * 0.5f * 255.0f;
        float py  = (yn + 1.0f) * 0.5f * 255.0f;
        float fx0 = floorf(px), fy0 = floorf(py);
        int   x0 = (int)fx0, y0 = (int)fy0;
        float pwx = px - fx0, pwy = py - fy0;
        int   x1 = x0 + 1, y1 = y0 + 1;
        float vx0 = (x0 >= 0 && x0 < ND2) ? 1.0f : 0.0f;
        float vx1 = (x1 >= 0 && x1 < ND2) ? 1.0f : 0.0f;
        float vy0 = (y0 >= 0 && y0 < ND2) ? 1.0f : 0.0f;
        float vy1 = (y1 >= 0 && y1 < ND2) ? 1.0f : 0.0f;
        int xc0 = clampi(x0, 0, ND2 - 1), xc1 = clampi(x1, 0, ND2 - 1);
        int yc0 = clampi(y0, 0, ND2 - 1), yc1 = clampi(y1, 0, ND2 - 1);
        float w00 = (1.0f - pwy) * (1.0f - pwx) * vy0 * vx0;
        float w01 = (1.0f - pwy) * pwx          * vy0 * vx1;
        float w10 = pwy          * (1.0f - pwx) * vy1 * vx0;
        float w11 = pwy          * pwx          * vy1 * vx1;

        // ---- loads: lines (global, b128) + plane taps (LDS, b128) ----
        const int ko = lq * 8;
        const float4* LX0 = (const float4*)(lx + ix * NC + ko);
        const float4* LX1 = (const float4*)(lx + (ix + 1) * NC + ko);
        const float4* LY0 = (const float4*)(ly + iy * NC + ko);
        const float4* LY1 = (const float4*)(ly + (iy + 1) * NC + ko);
        const float4 xa = LX0[0], xb = LX0[1], Xa = LX1[0], Xb = LX1[1];
        const float4 ya = LY0[0], yb = LY0[1], Ya = LY1[0], Yb = LY1[1];

        const int t00o = ((yc0 - py0) * PW + (xc0 - px0)) * PPADF + ko;
        const int t01o = ((yc0 - py0) * PW + (xc1 - px0)) * PPADF + ko;
        const int t10o = ((yc1 - py0) * PW + (xc0 - px0)) * PPADF + ko;
        const int t11o = ((yc1 - py0) * PW + (xc1 - px0)) * PPADF + ko;
        const float4 q00a = *(const float4*)&pls[t00o], q00b = *(const float4*)&pls[t00o + 4];
        const float4 q01a = *(const float4*)&pls[t01o], q01b = *(const float4*)&pls[t01o + 4];
        const float4 q10a = *(const float4*)&pls[t10o], q10b = *(const float4*)&pls[t10o + 4];
        const float4 q11a = *(const float4*)&pls[t11o], q11b = *(const float4*)&pls[t11o + 4];

        const float a0[8] = {xa.x, xa.y, xa.z, xa.w, xb.x, xb.y, xb.z, xb.w};
        const float a1[8] = {Xa.x, Xa.y, Xa.z, Xa.w, Xb.x, Xb.y, Xb.z, Xb.w};
        const float c0[8] = {ya.x, ya.y, ya.z, ya.w, yb.x, yb.y, yb.z, yb.w};
        const float c1[8] = {Ya.x, Ya.y, Ya.z, Ya.w, Yb.x, Yb.y, Yb.z, Yb.w};
        const float p00[8] = {q00a.x, q00a.y, q00a.z, q00a.w, q00b.x, q00b.y, q00b.z, q00b.w};
        const float p01[8] = {q01a.x, q01a.y, q01a.z, q01a.w, q01b.x, q01b.y, q01b.z, q01b.w};
        const float p10[8] = {q10a.x, q10a.y, q10a.z, q10a.w, q10b.x, q10b.y, q10b.z, q10b.w};
        const float p11[8] = {q11a.x, q11a.y, q11a.z, q11a.w, q11b.x, q11b.y, q11b.z, q11b.w};

        float f[8];
#pragma unroll
        for (int j = 0; j < 8; ++j) {
            const float fxv = a0[j] * omwx + a1[j] * wx;
            const float fyv = c0[j] * omwy + c1[j] * wy;
            const float fpv = p00[j] * w00 + p01[j] * w01 + p10[j] * w10 + p11[j] * w11;
            f[j] = fxv * fyv + fpv;
        }

        bf16x8 ahi, alo;
        pack_hilo(f, ahi, alo);

        // ---- decoder: 4 N-tiles x 3 hi/lo MFMAs, f32 accumulate ----
        float psum[4] = {0.0f, 0.0f, 0.0f, 0.0f};
#pragma unroll
        for (int nt = 0; nt < 4; ++nt) {
            f32x4 acc = {b1v[nt], b1v[nt], b1v[nt], b1v[nt]};
            acc = __builtin_amdgcn_mfma_f32_16x16x32_bf16(ahi, bhi[nt], acc, 0, 0, 0);
            acc = __builtin_amdgcn_mfma_f32_16x16x32_bf16(ahi, blo[nt], acc, 0, 0, 0);
            acc = __builtin_amdgcn_mfma_f32_16x16x32_bf16(alo, bhi[nt], acc, 0, 0, 0);
#pragma unroll
            for (int r = 0; r < 4; ++r)
                psum[r] = fmaf(fmaxf(acc[r], 0.0f), w2v[nt], psum[r]);
        }

        // ---- butterfly over the 16 hidden-column lanes (same lq group) ----
#pragma unroll
        for (int m = 1; m <= 8; m <<= 1) {
#pragma unroll
            for (int r = 0; r < 4; ++r)
                psum[r] += __shfl_xor(psum[r], m, 64);
        }

        // lane whose loaded pixel-row lcol falls in its own C row-group writes it
        if (lq == (lcol >> 2) && s < count)
            out[__float_as_int(rec.z)] = psum[lcol & 3] + b2s;
    }
}

// ---------------------------------------------------------------------------
// Fallback: unsorted fused kernel (MODE 1 transposed tables / MODE 0 raw).
// ---------------------------------------------------------------------------
template <int MODE>
__global__ __launch_bounds__(256) void fused_forward(
    const float* __restrict__ coords, const float* __restrict__ lx,
    const float* __restrict__ ly, const float* __restrict__ pl,
    const float* __restrict__ W1, const float* __restrict__ b1,
    const float* __restrict__ W2, const float* __restrict__ b2,
    float* __restrict__ out)
{
    const int i = blockIdx.x * 256 + threadIdx.x;
    const float2 xy = reinterpret_cast<const float2*>(coords)[i];
    const float xn = xy.x * (2.0f / 1024.0f) - 1.0f;
    const float yn = xy.y * (2.0f / 1024.0f) - 1.0f;

    float posx = fminf(fmaxf((xn + 1.0f) * 0.5f * 1023.0f, 0.0f), 1023.0f);
    int   ix   = min((int)posx, 1022);
    float wx   = posx - (float)ix, omwx = 1.0f - wx;
    float posy = fminf(fmaxf((yn + 1.0f) * 0.5f * 1023.0f, 0.0f), 1023.0f);
    int   iy   = min((int)posy, 1022);
    float wy   = posy - (float)iy, omwy = 1.0f - wy;

    float px  = (xn + 1.0f) * 0.5f * 255.0f;
    float py  = (yn + 1.0f) * 0.5f * 255.0f;
    float fx0 = floorf(px), fy0 = floorf(py);
    int   x0 = (int)fx0, y0 = (int)fy0;
    float pwx = px - fx0, pwy = py - fy0;
    int   x1 = x0 + 1, y1 = y0 + 1;
    float vx0 = (x0 >= 0 && x0 < ND2) ? 1.0f : 0.0f;
    float vx1 = (x1 >= 0 && x1 < ND2) ? 1.0f : 0.0f;
    float vy0 = (y0 >= 0 && y0 < ND2) ? 1.0f : 0.0f;
    float vy1 = (y1 >= 0 && y1 < ND2) ? 1.0f : 0.0f;
    int xc0 = clampi(x0, 0, ND2 - 1), xc1 = clampi(x1, 0, ND2 - 1);
    int yc0 = clampi(y0, 0, ND2 - 1), yc1 = clampi(y1, 0, ND2 - 1);
    float w00 = (1.0f - pwy) * (1.0f - pwx) * vy0 * vx0;
    float w01 = (1.0f - pwy) * pwx          * vy0 * vx1;
    float w10 = pwy          * (1.0f - pwx) * vy1 * vx0;
    float w11 = pwy          * pwx          * vy1 * vx1;

    float feat[NC];
    if (MODE == 1) {
        const float4* ax0 = (const float4*)(lx + ix * NC);
        const float4* ax1 = (const float4*)(lx + (ix + 1) * NC);
        const float4* ay0 = (const float4*)(ly + iy * NC);
        const float4* ay1 = (const float4*)(ly + (iy + 1) * NC);
        const float4* p00 = (const float4*)(pl + (yc0 * ND2 + xc0) * NC);
        const float4* p01 = (const float4*)(pl + (yc0 * ND2 + xc1) * NC);
        const float4* p10 = (const float4*)(pl + (yc1 * ND2 + xc0) * NC);
        const float4* p11 = (const float4*)(pl + (yc1 * ND2 + xc1) * NC);
#pragma unroll
        for (int k = 0; k < 8; ++k) {
            float4 a0 = ax0[k], a1 = ax1[k], c0 = ay0[k], c1 = ay1[k];
            float4 q00 = p00[k], q01 = p01[k], q10 = p10[k], q11 = p11[k];
#define FC(j, comp)                                                          \
            {                                                                \
                float fxv = a0.comp * omwx + a1.comp * wx;                   \
                float fyv = c0.comp * omwy + c1.comp * wy;                   \
                float fpv = q00.comp * w00 + q01.comp * w01 +                \
                            q10.comp * w10 + q11.comp * w11;                 \
                feat[k * 4 + j] = fxv * fyv + fpv;                           \
            }
            FC(0, x) FC(1, y) FC(2, z) FC(3, w)
#undef FC
        }
    } else {
#pragma unroll
        for (int c = 0; c < NC; ++c) {
            float a0 = lx[c * ND1 + ix], a1 = lx[c * ND1 + ix + 1];
            float c0 = ly[c * ND1 + iy], c1 = ly[c * ND1 + iy + 1];
            const float* ps = pl + c * (ND2 * ND2);
            float q00 = ps[yc0 * ND2 + xc0], q01 = ps[yc0 * ND2 + xc1];
            float q10 = ps[yc1 * ND2 + xc0], q11 = ps[yc1 * ND2 + xc1];
            feat[c] = (a0 * omwx + a1 * wx) * (c0 * omwy + c1 * wy)
                    + (q00 * w00 + q01 * w01 + q10 * w10 + q11 * w11);
        }
    }

    float acc = b2[0];
#pragma unroll 4
    for (int m = 0; m < NM; ++m) {
        const float4* wrow = (const float4*)(W1 + m * NC);
        float a = b1[m];
#pragma unroll
        for (int k = 0; k < 8; ++k) {
            float4 wv = wrow[k];
            a = fmaf(feat[k * 4 + 0], wv.x, a);
            a = fmaf(feat[k * 4 + 1], wv.y, a);
            a = fmaf(feat[k * 4 + 2], wv.z, a);
            a = fmaf(feat[k * 4 + 3], wv.w, a);
        }
        acc = fmaf(fmaxf(a, 0.0f), W2[m], acc);
    }
    out[i] = acc;
}

// ---------------------------------------------------------------------------
extern "C" void kernel_launch(void* const* d_in, const int* in_sizes, int n_in,
                              void* d_out, int out_size, void* d_ws, size_t ws_size,
                              hipStream_t stream) {
    const float* coords = (const float*)d_in[0];
    const float* lfx    = (const float*)d_in[1];
    const float* lfy    = (const float*)d_in[2];
    const float* plane  = (const float*)d_in[3];
    const float* W1     = (const float*)d_in[4];
    const float* b1     = (const float*)d_in[5];
    const float* W2     = (const float*)d_in[6];
    const float* b2     = (const float*)d_in[7];
    float* out = (float*)d_out;

    const size_t planeBytes = (size_t)ND2 * ND2 * NC * sizeof(float); // 8 MB
    const size_t lineBytes  = (size_t)ND1 * NC * sizeof(float);       // 128 KB
    const size_t slotsBytes = (size_t)NSLOT * sizeof(float4);         // 18.9 MB
    const size_t needTrans  = planeBytes + 2 * lineBytes;
    const size_t needFull   = needTrans + slotsBytes + NBUCK * sizeof(int);

    if (ws_size >= needFull) {
        char* p = (char*)d_ws;
        float*  pl_t   = (float*)p;   p += planeBytes;   // unused in full path
        float*  lx_t   = (float*)p;   p += lineBytes;
        float*  ly_t   = (float*)p;   p += lineBytes;
        float4* slots  = (float4*)p;  p += slotsBytes;
        int*    cursor = (int*)p;

        // ws is re-poisoned each call -> everything rebuilt every call.
        pass1_prepare<<<33, 256, 0, stream>>>(plane, lfx, lfy,
                                              pl_t, lx_t, ly_t, cursor);
        scatter_slack<<<NPIX / 4096, 1024, 0, stream>>>((const float2*)coords,
                                                        cursor, slots);
        fused_mfma<<<NBUCK * FBLK, FTH, 0, stream>>>(slots, cursor, lx_t, ly_t,
                                                     plane, W1, b1, W2, b2, out);
    } else if (ws_size >= needTrans) {
        float* pl_t = (float*)d_ws;
        float* lx_t = (float*)((char*)d_ws + planeBytes);
        float* ly_t = lx_t + ND1 * NC;
        pass1_prepare<<<1057, 256, 0, stream>>>(plane, lfx, lfy,
                                                pl_t, lx_t, ly_t, nullptr);
        fused_forward<1><<<NPIX / 256, 256, 0, stream>>>(
            coords, lx_t, ly_t, pl_t, W1, b1, W2, b2, out);
    } else {
        fused_forward<0><<<NPIX / 256, 256, 0, stream>>>(
            coords, lfx, lfy, plane, W1, b1, W2, b2, out);
    }
}

// Round 12
// 177.594 us; speedup vs baseline: 1.0988x; 1.0988x over previous
//
#include <hip/hip_runtime.h>

// Problem constants (from reference)
#define NC   32      // feature channels
#define ND1  1024    // line resolution
#define ND2  256     // plane resolution
#define NM   64      // hidden width
#define NPIX (1024 * 1024)
#define NBUCK 256    // 16x16 coarse buckets, each 64x64 coordinate units
#define CAP  4608    // slots per bucket (mean 4096 + 8 sigma)
#define NSLOT (NBUCK * CAP)
#define PW   18      // plane window: 18x18 texels covers any bucket's taps
#define PWS  40      // shorts per texel in LDS (32 bf16 + pad; 80B, 16B-aligned)
#define FBLK 4       // fused blocks per bucket
#define FTH  512     // fused block size
#define PART_SLOTS (CAP / FBLK)     // 1152
#define PART_CHUNKS (PART_SLOTS/16) // 72 chunks of 16 pixels

typedef __attribute__((ext_vector_type(8))) short bf16x8;  // 8 bf16 (4 VGPRs)
typedef __attribute__((ext_vector_type(4))) float f32x4;

__device__ __forceinline__ int clampi(int v, int lo, int hi) {
    return min(max(v, lo), hi);
}

// RNE-ish f32 -> bf16 (u16), ignoring tie-to-even (values are finite/small).
__device__ __forceinline__ unsigned int bf16rne(float f) {
    return (__float_as_uint(f) + 0x8000u) >> 16;
}

// Split 8 f32 into bf16 hi (truncate) + bf16 lo (exact residual, truncated).
// hi + lo = f with |err| <= 2^-16 |f| per element.
__device__ __forceinline__ void pack_hilo(const float* f, bf16x8& hi, bf16x8& lo) {
    union { unsigned int u[4]; bf16x8 v; } H, L;
#pragma unroll
    for (int j = 0; j < 4; ++j) {
        unsigned int b0 = __float_as_uint(f[2 * j]);
        unsigned int b1 = __float_as_uint(f[2 * j + 1]);
        unsigned int h0 = b0 & 0xFFFF0000u, h1 = b1 & 0xFFFF0000u;
        H.u[j] = (h0 >> 16) | h1;
        float l0 = f[2 * j]     - __uint_as_float(h0);   // exact
        float l1 = f[2 * j + 1] - __uint_as_float(h1);   // exact
        L.u[j] = (__float_as_uint(l0) >> 16) | (__float_as_uint(l1) & 0xFFFF0000u);
    }
    hi = H.v; lo = L.v;
}

// ---------------------------------------------------------------------------
// Pass 1: line transposes (blocks 0..31), cursor init (32), plane transpose
// (33..1056) -> pl_t [65536][32] used for coalesced window staging.
// ---------------------------------------------------------------------------
__global__ __launch_bounds__(256) void pass1_prepare(
    const float* __restrict__ plane, const float* __restrict__ lfx,
    const float* __restrict__ lfy, float* __restrict__ pl_t,
    float* __restrict__ lx_t, float* __restrict__ ly_t, int* __restrict__ cursor)
{
    __shared__ float tile[32][65];
    const int blk = blockIdx.x, tid = threadIdx.x;
    const float* in; float* out; int N, pos0;
    if (blk < 16)       { in = lfx;   out = lx_t; N = 1024;  pos0 = blk * 64; }
    else if (blk < 32)  { in = lfy;   out = ly_t; N = 1024;  pos0 = (blk - 16) * 64; }
    else if (blk == 32) { if (cursor && tid < NBUCK) cursor[tid] = tid * CAP; return; }
    else                { in = plane; out = pl_t; N = 65536; pos0 = (blk - 33) * 64; }
#pragma unroll
    for (int r = 0; r < 8; ++r) {
        int c = r * 4 + (tid >> 6), p = tid & 63;
        tile[c][p] = in[c * N + pos0 + p];
    }
    __syncthreads();
#pragma unroll
    for (int r = 0; r < 8; ++r) {
        int p = r * 8 + (tid >> 5), c = tid & 31;
        out[(pos0 + p) * 32 + c] = tile[c][p];
    }
}

// ---------------------------------------------------------------------------
// Pass 2: slack-bucket scatter. First pass records per-record offsets while
// counting; one global atomicAdd per (block,bucket) reserves a window; writes
// are bucket-windowed 16B records. (Second count round removed vs round 9.)
// ---------------------------------------------------------------------------
__global__ __launch_bounds__(1024) void scatter_slack(
    const float2* __restrict__ coords, int* __restrict__ cursor,
    float4* __restrict__ slots)
{
    __shared__ int h[NBUCK];
    __shared__ int basew[NBUCK];
    const int t = threadIdx.x;
    if (t < NBUCK) h[t] = 0;
    __syncthreads();
    const int base_i = blockIdx.x * 4096;
    float2 xy[4]; int cell[4]; int off[4];
#pragma unroll
    for (int r = 0; r < 4; ++r) {
        xy[r] = coords[base_i + r * 1024 + t];
        const int xi = clampi((int)xy[r].x, 0, 1023);
        const int yi = clampi((int)xy[r].y, 0, 1023);
        cell[r] = ((yi >> 6) << 4) | (xi >> 6);
        off[r] = atomicAdd(&h[cell[r]], 1);             // count + unique offset
    }
    __syncthreads();
    if (t < NBUCK) {
        const int n = h[t];
        basew[t] = n ? atomicAdd(&cursor[t], n) : 0;
    }
    __syncthreads();
#pragma unroll
    for (int r = 0; r < 4; ++r) {
        const int dst = min(basew[cell[r]] + off[r], NSLOT - 1); // defensive
        slots[dst] = make_float4(xy[r].x, xy[r].y,
                                 __int_as_float(base_i + r * 1024 + t), 0.0f);
    }
}

// ---------------------------------------------------------------------------
// Pass 3: MFMA fused kernel. Wave processes 16 pixels/iter: lane l
// interpolates pixel (l&15), channels (l>>4)*8..+8 == A-fragment of
// mfma_f32_16x16x32_bf16. Plane window in LDS as bf16 (26 KB -> 4 blocks/CU,
// 32 waves/CU). W1 hi/lo bf16 B-fragments in regs. Layer 2 via 16-lane
// shfl_xor butterfly.
// ---------------------------------------------------------------------------
__global__ __launch_bounds__(FTH, 4) void fused_mfma(
    const float4* __restrict__ slots, const int* __restrict__ cursor,
    const float* __restrict__ lx,    // [1024][32] transposed
    const float* __restrict__ ly,
    const float* __restrict__ pl,    // [65536][32] transposed
    const float* __restrict__ W1, const float* __restrict__ b1,
    const float* __restrict__ W2, const float* __restrict__ b2,
    float* __restrict__ out)
{
    const int b    = blockIdx.x / FBLK;
    const int part = blockIdx.x - b * FBLK;
    const int t    = threadIdx.x;
    const int wid  = t >> 6;
    const int lane = t & 63;
    const int lcol = lane & 15;   // A-row (pixel) / B,C-col (hidden)
    const int lq   = lane >> 4;   // k-slice / C row group
    const int bx = b & 15, by = b >> 4;
    const int px0 = (int)(bx * 15.9375f);
    const int py0 = (int)(by * 15.9375f);

    // ---- stage plane window (bf16): pls[tex][ch], 40 shorts/texel = 80B ----
    __shared__ __align__(16) unsigned short pls[PW * PW * PWS];   // 25.9 KB
    for (int i = t; i < PW * PW * 8; i += FTH) {
        const int tex = i >> 3, k4 = i & 7;            // 4 channels per slot
        const int ty = tex / PW, tx = tex - ty * PW;
        const int gy = min(py0 + ty, ND2 - 1), gx = min(px0 + tx, ND2 - 1);
        const float4 v = ((const float4*)pl)[((gy << 8) + gx) * 8 + k4];
        uint2 pk;
        pk.x = bf16rne(v.x) | (bf16rne(v.y) << 16);
        pk.y = bf16rne(v.z) | (bf16rne(v.w) << 16);
        *(uint2*)&pls[tex * PWS + k4 * 4] = pk;
    }

    // ---- preload B fragments (W1 hi/lo), b1, W2 scalars ----
    bf16x8 bhi[4], blo[4];
    float b1v[4], w2v[4];
#pragma unroll
    for (int nt = 0; nt < 4; ++nt) {
        const int row = nt * 16 + lcol;
        const float4* wr = (const float4*)(W1 + row * NC + lq * 8);
        const float4 wa = wr[0], wb = wr[1];
        float wf[8] = {wa.x, wa.y, wa.z, wa.w, wb.x, wb.y, wb.z, wb.w};
        pack_hilo(wf, bhi[nt], blo[nt]);
        b1v[nt] = b1[row];
        w2v[nt] = W2[row];
    }
    const float b2s = b2[0];
    __syncthreads();

    const int base  = b * CAP;
    const int count = min(cursor[b] - base, CAP);

    for (int ci = wid; ci < PART_CHUNKS; ci += FTH / 64) {
        const int chunk = part * PART_SLOTS + ci * 16;
        if (chunk >= count) break;                   // wave-uniform
        const int s = chunk + lcol;
        const float4 rec = slots[base + min(s, count - 1)];
        const float x = rec.x, y = rec.y;

        const float xn = x * (2.0f / 1024.0f) - 1.0f;
        const float yn = y * (2.0f / 1024.0f) - 1.0f;

        // ---- 1D line interp (border clamp, align_corners) ----
        float posx = fminf(fmaxf((xn + 1.0f) * 0.5f * 1023.0f, 0.0f), 1023.0f);
        int   ix   = min((int)posx, 1022);
        float wx   = posx - (float)ix, omwx = 1.0f - wx;
        float posy = fminf(fmaxf((yn + 1.0f) * 0.5f * 1023.0f, 0.0f), 1023.0f);
        int   iy   = min((int)posy, 1022);
        float wy   = posy - (float)iy, omwy = 1.0f - wy;

        // ---- plane bilinear (zeros padding, align_corners) ----
        float px  = (xn + 1.0f) * 0.5f * 255.0f;
        float py  = (yn + 1.0f) * 0.5f * 255.0f;
        float fx0 = floorf(px), fy0 = floorf(py);
        int   x0 = (int)fx0, y0 = (int)fy0;
        float pwx = px - fx0, pwy = py - fy0;
        int   x1 = x0 + 1, y1 = y0 + 1;
        float vx0 = (x0 >= 0 && x0 < ND2) ? 1.0f : 0.0f;
        float vx1 = (x1 >= 0 && x1 < ND2) ? 1.0f : 0.0f;
        float vy0 = (y0 >= 0 && y0 < ND2) ? 1.0f : 0.0f;
        float vy1 = (y1 >= 0 && y1 < ND2) ? 1.0f : 0.0f;
        int xc0 = clampi(x0, 0, ND2 - 1), xc1 = clampi(x1, 0, ND2 - 1);
        int yc0 = clampi(y0, 0, ND2 - 1), yc1 = clampi(y1, 0, ND2 - 1);
        float w00 = (1.0f - pwy) * (1.0f - pwx) * vy0 * vx0;
        float w01 = (1.0f - pwy) * pwx          * vy0 * vx1;
        float w10 = pwy          * (1.0f - pwx) * vy1 * vx0;
        float w11 = pwy          * pwx          * vy1 * vx1;

        // ---- loads: lines (global, b128) + plane taps (LDS b128, bf16) ----
        const int ko = lq * 8;
        const float4* LX0 = (const float4*)(lx + ix * NC + ko);
        const float4* LX1 = (const float4*)(lx + (ix + 1) * NC + ko);
        const float4* LY0 = (const float4*)(ly + iy * NC + ko);
        const float4* LY1 = (const float4*)(ly + (iy + 1) * NC + ko);
        const float4 xa = LX0[0], xb = LX0[1], Xa = LX1[0], Xb = LX1[1];
        const float4 ya = LY0[0], yb = LY0[1], Ya = LY1[0], Yb = LY1[1];

        const uint4 u00 = *(const uint4*)&pls[((yc0 - py0) * PW + (xc0 - px0)) * PWS + ko];
        const uint4 u01 = *(const uint4*)&pls[((yc0 - py0) * PW + (xc1 - px0)) * PWS + ko];
        const uint4 u10 = *(const uint4*)&pls[((yc1 - py0) * PW + (xc0 - px0)) * PWS + ko];
        const uint4 u11 = *(const uint4*)&pls[((yc1 - py0) * PW + (xc1 - px0)) * PWS + ko];

        const float a0[8] = {xa.x, xa.y, xa.z, xa.w, xb.x, xb.y, xb.z, xb.w};
        const float a1[8] = {Xa.x, Xa.y, Xa.z, Xa.w, Xb.x, Xb.y, Xb.z, Xb.w};
        const float c0[8] = {ya.x, ya.y, ya.z, ya.w, yb.x, yb.y, yb.z, yb.w};
        const float c1[8] = {Ya.x, Ya.y, Ya.z, Ya.w, Yb.x, Yb.y, Yb.z, Yb.w};

        const unsigned int uu00[4] = {u00.x, u00.y, u00.z, u00.w};
        const unsigned int uu01[4] = {u01.x, u01.y, u01.z, u01.w};
        const unsigned int uu10[4] = {u10.x, u10.y, u10.z, u10.w};
        const unsigned int uu11[4] = {u11.x, u11.y, u11.z, u11.w};

        float f[8];
#pragma unroll
        for (int j2 = 0; j2 < 4; ++j2) {               // pairs of channels
            const float p00a = __uint_as_float(uu00[j2] << 16);
            const float p00b = __uint_as_float(uu00[j2] & 0xFFFF0000u);
            const float p01a = __uint_as_float(uu01[j2] << 16);
            const float p01b = __uint_as_float(uu01[j2] & 0xFFFF0000u);
            const float p10a = __uint_as_float(uu10[j2] << 16);
            const float p10b = __uint_as_float(uu10[j2] & 0xFFFF0000u);
            const float p11a = __uint_as_float(uu11[j2] << 16);
            const float p11b = __uint_as_float(uu11[j2] & 0xFFFF0000u);
            const int j = j2 * 2;
            {
                const float fxv = a0[j] * omwx + a1[j] * wx;
                const float fyv = c0[j] * omwy + c1[j] * wy;
                const float fpv = p00a * w00 + p01a * w01 + p10a * w10 + p11a * w11;
                f[j] = fxv * fyv + fpv;
            }
            {
                const float fxv = a0[j + 1] * omwx + a1[j + 1] * wx;
                const float fyv = c0[j + 1] * omwy + c1[j + 1] * wy;
                const float fpv = p00b * w00 + p01b * w01 + p10b * w10 + p11b * w11;
                f[j + 1] = fxv * fyv + fpv;
            }
        }

        bf16x8 ahi, alo;
        pack_hilo(f, ahi, alo);

        // ---- decoder: 4 N-tiles x 3 hi/lo MFMAs, f32 accumulate ----
        float psum[4] = {0.0f, 0.0f, 0.0f, 0.0f};
#pragma unroll
        for (int nt = 0; nt < 4; ++nt) {
            f32x4 acc = {b1v[nt], b1v[nt], b1v[nt], b1v[nt]};
            acc = __builtin_amdgcn_mfma_f32_16x16x32_bf16(ahi, bhi[nt], acc, 0, 0, 0);
            acc = __builtin_amdgcn_mfma_f32_16x16x32_bf16(ahi, blo[nt], acc, 0, 0, 0);
            acc = __builtin_amdgcn_mfma_f32_16x16x32_bf16(alo, bhi[nt], acc, 0, 0, 0);
#pragma unroll
            for (int r = 0; r < 4; ++r)
                psum[r] = fmaf(fmaxf(acc[r], 0.0f), w2v[nt], psum[r]);
        }

        // ---- butterfly over the 16 hidden-column lanes (same lq group) ----
#pragma unroll
        for (int m = 1; m <= 8; m <<= 1) {
#pragma unroll
            for (int r = 0; r < 4; ++r)
                psum[r] += __shfl_xor(psum[r], m, 64);
        }

        // lane whose loaded pixel-row lcol falls in its own C row-group writes
        if (lq == (lcol >> 2) && s < count)
            out[__float_as_int(rec.z)] = psum[lcol & 3] + b2s;
    }
}

// ---------------------------------------------------------------------------
// Fallback: unsorted fused kernel (MODE 1 transposed tables / MODE 0 raw).
// ---------------------------------------------------------------------------
template <int MODE>
__global__ __launch_bounds__(256) void fused_forward(
    const float* __restrict__ coords, const float* __restrict__ lx,
    const float* __restrict__ ly, const float* __restrict__ pl,
    const float* __restrict__ W1, const float* __restrict__ b1,
    const float* __restrict__ W2, const float* __restrict__ b2,
    float* __restrict__ out)
{
    const int i = blockIdx.x * 256 + threadIdx.x;
    const float2 xy = reinterpret_cast<const float2*>(coords)[i];
    const float xn = xy.x * (2.0f / 1024.0f) - 1.0f;
    const float yn = xy.y * (2.0f / 1024.0f) - 1.0f;

    float posx = fminf(fmaxf((xn + 1.0f) * 0.5f * 1023.0f, 0.0f), 1023.0f);
    int   ix   = min((int)posx, 1022);
    float wx   = posx - (float)ix, omwx = 1.0f - wx;
    float posy = fminf(fmaxf((yn + 1.0f) * 0.5f * 1023.0f, 0.0f), 1023.0f);
    int   iy   = min((int)posy, 1022);
    float wy   = posy - (float)iy, omwy = 1.0f - wy;

    float px  = (xn + 1.0f) * 0.5f * 255.0f;
    float py  = (yn + 1.0f) * 0.5f * 255.0f;
    float fx0 = floorf(px), fy0 = floorf(py);
    int   x0 = (int)fx0, y0 = (int)fy0;
    float pwx = px - fx0, pwy = py - fy0;
    int   x1 = x0 + 1, y1 = y0 + 1;
    float vx0 = (x0 >= 0 && x0 < ND2) ? 1.0f : 0.0f;
    float vx1 = (x1 >= 0 && x1 < ND2) ? 1.0f : 0.0f;
    float vy0 = (y0 >= 0 && y0 < ND2) ? 1.0f : 0.0f;
    float vy1 = (y1 >= 0 && y1 < ND2) ? 1.0f : 0.0f;
    int xc0 = clampi(x0, 0, ND2 - 1), xc1 = clampi(x1, 0, ND2 - 1);
    int yc0 = clampi(y0, 0, ND2 - 1), yc1 = clampi(y1, 0, ND2 - 1);
    float w00 = (1.0f - pwy) * (1.0f - pwx) * vy0 * vx0;
    float w01 = (1.0f - pwy) * pwx          * vy0 * vx1;
    float w10 = pwy          * (1.0f - pwx) * vy1 * vx0;
    float w11 = pwy          * pwx          * vy1 * vx1;

    float feat[NC];
    if (MODE == 1) {
        const float4* ax0 = (const float4*)(lx + ix * NC);
        const float4* ax1 = (const float4*)(lx + (ix + 1) * NC);
        const float4* ay0 = (const float4*)(ly + iy * NC);
        const float4* ay1 = (const float4*)(ly + (iy + 1) * NC);
        const float4* p00 = (const float4*)(pl + (yc0 * ND2 + xc0) * NC);
        const float4* p01 = (const float4*)(pl + (yc0 * ND2 + xc1) * NC);
        const float4* p10 = (const float4*)(pl + (yc1 * ND2 + xc0) * NC);
        const float4* p11 = (const float4*)(pl + (yc1 * ND2 + xc1) * NC);
#pragma unroll
        for (int k = 0; k < 8; ++k) {
            float4 a0 = ax0[k], a1 = ax1[k], c0 = ay0[k], c1 = ay1[k];
            float4 q00 = p00[k], q01 = p01[k], q10 = p10[k], q11 = p11[k];
#define FC(j, comp)                                                          \
            {                                                                \
                float fxv = a0.comp * omwx + a1.comp * wx;                   \
                float fyv = c0.comp * omwy + c1.comp * wy;                   \
                float fpv = q00.comp * w00 + q01.comp * w01 +                \
                            q10.comp * w10 + q11.comp * w11;                 \
                feat[k * 4 + j] = fxv * fyv + fpv;                           \
            }
            FC(0, x) FC(1, y) FC(2, z) FC(3, w)
#undef FC
        }
    } else {
#pragma unroll
        for (int c = 0; c < NC; ++c) {
            float a0 = lx[c * ND1 + ix], a1 = lx[c * ND1 + ix + 1];
            float c0 = ly[c * ND1 + iy], c1 = ly[c * ND1 + iy + 1];
            const float* ps = pl + c * (ND2 * ND2);
            float q00 = ps[yc0 * ND2 + xc0], q01 = ps[yc0 * ND2 + xc1];
            float q10 = ps[yc1 * ND2 + xc0], q11 = ps[yc1 * ND2 + xc1];
            feat[c] = (a0 * omwx + a1 * wx) * (c0 * omwy + c1 * wy)
                    + (q00 * w00 + q01 * w01 + q10 * w10 + q11 * w11);
        }
    }

    float acc = b2[0];
#pragma unroll 4
    for (int m = 0; m < NM; ++m) {
        const float4* wrow = (const float4*)(W1 + m * NC);
        float a = b1[m];
#pragma unroll
        for (int k = 0; k < 8; ++k) {
            float4 wv = wrow[k];
            a = fmaf(feat[k * 4 + 0], wv.x, a);
            a = fmaf(feat[k * 4 + 1], wv.y, a);
            a = fmaf(feat[k * 4 + 2], wv.z, a);
            a = fmaf(feat[k * 4 + 3], wv.w, a);
        }
        acc = fmaf(fmaxf(a, 0.0f), W2[m], acc);
    }
    out[i] = acc;
}

// ---------------------------------------------------------------------------
extern "C" void kernel_launch(void* const* d_in, const int* in_sizes, int n_in,
                              void* d_out, int out_size, void* d_ws, size_t ws_size,
                              hipStream_t stream) {
    const float* coords = (const float*)d_in[0];
    const float* lfx    = (const float*)d_in[1];
    const float* lfy    = (const float*)d_in[2];
    const float* plane  = (const float*)d_in[3];
    const float* W1     = (const float*)d_in[4];
    const float* b1     = (const float*)d_in[5];
    const float* W2     = (const float*)d_in[6];
    const float* b2     = (const float*)d_in[7];
    float* out = (float*)d_out;

    const size_t planeBytes = (size_t)ND2 * ND2 * NC * sizeof(float); // 8 MB
    const size_t lineBytes  = (size_t)ND1 * NC * sizeof(float);       // 128 KB
    const size_t slotsBytes = (size_t)NSLOT * sizeof(float4);         // 18.9 MB
    const size_t needTrans  = planeBytes + 2 * lineBytes;
    const size_t needFull   = needTrans + slotsBytes + NBUCK * sizeof(int);

    if (ws_size >= needFull) {
        char* p = (char*)d_ws;
        float*  pl_t   = (float*)p;   p += planeBytes;
        float*  lx_t   = (float*)p;   p += lineBytes;
        float*  ly_t   = (float*)p;   p += lineBytes;
        float4* slots  = (float4*)p;  p += slotsBytes;
        int*    cursor = (int*)p;

        // ws is re-poisoned each call -> everything rebuilt every call.
        pass1_prepare<<<1057, 256, 0, stream>>>(plane, lfx, lfy,
                                                pl_t, lx_t, ly_t, cursor);
        scatter_slack<<<NPIX / 4096, 1024, 0, stream>>>((const float2*)coords,
                                                        cursor, slots);
        fused_mfma<<<NBUCK * FBLK, FTH, 0, stream>>>(slots, cursor, lx_t, ly_t,
                                                     pl_t, W1, b1, W2, b2, out);
    } else if (ws_size >= needTrans) {
        float* pl_t = (float*)d_ws;
        float* lx_t = (float*)((char*)d_ws + planeBytes);
        float* ly_t = lx_t + ND1 * NC;
        pass1_prepare<<<1057, 256, 0, stream>>>(plane, lfx, lfy,
                                                pl_t, lx_t, ly_t, nullptr);
        fused_forward<1><<<NPIX / 256, 256, 0, stream>>>(
            coords, lx_t, ly_t, pl_t, W1, b1, W2, b2, out);
    } else {
        fused_forward<0><<<NPIX / 256, 256, 0, stream>>>(
            coords, lfx, lfy, plane, W1, b1, W2, b2, out);
    }
}